// Round 1
// baseline (7906.525 us; speedup 1.0000x reference)
//
#include <hip/hip_runtime.h>
#include <hip/hip_bf16.h>

#define HW 4096
#define CCH 256

__device__ __forceinline__ float bf2f(__hip_bfloat16 v) { return __bfloat162float(v); }
__device__ __forceinline__ __hip_bfloat16 f2bf(float v) { return __float2bfloat16(v); }

// ---------------- Kernel A: channel-attention gating: xg = x * sigmoid(MLP(x)) ----------------
__global__ __launch_bounds__(256) void ka_ca(
    const float* __restrict__ x, const float* __restrict__ w1, const float* __restrict__ b1,
    const float* __restrict__ w2, const float* __restrict__ b2, float* __restrict__ xg)
{
  int p = blockIdx.x * 256 + threadIdx.x;          // pixel id, 0..131071
  int b = p >> 12, rem = p & 4095;
  const float* xp = x  + (size_t)b * CCH * HW + rem;
  float*       xo = xg + (size_t)b * CCH * HW + rem;

  float h1[64];
  #pragma unroll
  for (int j = 0; j < 64; ++j) h1[j] = b1[j];

  for (int c = 0; c < 256; ++c) {
    float xv = xp[c * HW];
    const float* wr = w1 + c * 64;                 // wave-uniform, scalar loads
    #pragma unroll
    for (int j = 0; j < 64; ++j) h1[j] += xv * wr[j];
  }
  #pragma unroll
  for (int j = 0; j < 64; ++j) h1[j] = fmaxf(h1[j], 0.f);

  for (int c0 = 0; c0 < 256; c0 += 4) {
    float a0 = b2[c0], a1 = b2[c0+1], a2 = b2[c0+2], a3 = b2[c0+3];
    #pragma unroll 8
    for (int j = 0; j < 64; ++j) {
      float hv = h1[j];
      const float4 w = *reinterpret_cast<const float4*>(w2 + j * 256 + c0);
      a0 += hv * w.x; a1 += hv * w.y; a2 += hv * w.z; a3 += hv * w.w;
    }
    float x0 = xp[(c0+0) * HW], x1v = xp[(c0+1) * HW];
    float x2v = xp[(c0+2) * HW], x3 = xp[(c0+3) * HW];
    xo[(c0+0) * HW] = x0  / (1.f + __expf(-a0));
    xo[(c0+1) * HW] = x1v / (1.f + __expf(-a1));
    xo[(c0+2) * HW] = x2v / (1.f + __expf(-a2));
    xo[(c0+3) * HW] = x3  / (1.f + __expf(-a3));
  }
}

// ---------------- Kernel B: windowed MHSA + out-proj + residual (in-place on xg) ----------------
__global__ __launch_bounds__(256) void kb_attn(
    float* __restrict__ x2,
    const float* __restrict__ qkv_w, const float* __restrict__ qkv_b,
    const float* __restrict__ out_w, const float* __restrict__ out_b)
{
  __shared__ __hip_bfloat16 sXW[256 * 64];   // [c][t]   32768 B
  __shared__ float sQ[64 * 65];              // [t][d]   16640 B
  __shared__ float sK[64 * 65];
  __shared__ float sV[64 * 65];
  __shared__ __hip_bfloat16 sP[64 * 64];     // [r][j]    8192 B
  __shared__ float sO[64 * 257];             // [t][c]   65792 B   (total 156672 B)

  const int tid  = threadIdx.x;
  const int lane = tid & 63;
  const int wv   = __builtin_amdgcn_readfirstlane(tid >> 6);
  const int wid  = blockIdx.x;
  const int b    = wid >> 6, wrem = wid & 63;
  const int pbase = (wrem >> 3) * 8 * 64 + (wrem & 7) * 8;
  float* img = x2 + (size_t)b * CCH * HW;
  const int pix = pbase + (lane >> 3) * 64 + (lane & 7);   // token 'lane' pixel offset

  // stage 1: window -> LDS (bf16, channel-major)
  for (int it = 0; it < 64; ++it) {
    int c = it * 4 + wv;
    sXW[c * 64 + lane] = f2bf(img[c * HW + pix]);
  }
  __syncthreads();

  const int wv16 = wv * 16;
  for (int h = 0; h < 4; ++h) {
    // ---- qkv for head h: lane = token, wave = 16-dim slice ----
    const int colq = h * 64 + wv16;
    float qa[16], ka[16], va[16];
    #pragma unroll
    for (int d = 0; d < 16; ++d) {
      qa[d] = qkv_b[colq + d];
      ka[d] = qkv_b[256 + colq + d];
      va[d] = qkv_b[512 + colq + d];
    }
    for (int c = 0; c < 256; ++c) {
      float xv = bf2f(sXW[c * 64 + lane]);
      const float* wr = qkv_w + c * 768 + colq;            // wave-uniform rows
      #pragma unroll
      for (int d = 0; d < 16; ++d) qa[d] += xv * wr[d];
      #pragma unroll
      for (int d = 0; d < 16; ++d) ka[d] += xv * wr[256 + d];
      #pragma unroll
      for (int d = 0; d < 16; ++d) va[d] += xv * wr[512 + d];
    }
    #pragma unroll
    for (int d = 0; d < 16; ++d) {
      sQ[lane * 65 + wv16 + d] = qa[d];
      sK[lane * 65 + wv16 + d] = ka[d];
      sV[lane * 65 + wv16 + d] = va[d];
    }
    __syncthreads();

    // ---- scores + softmax: lane = key col j, rows wv16..wv16+15 ----
    float sc[16];
    #pragma unroll
    for (int r = 0; r < 16; ++r) sc[r] = 0.f;
    for (int d = 0; d < 64; ++d) {
      float kv = sK[lane * 65 + d];
      #pragma unroll
      for (int r = 0; r < 16; ++r) sc[r] += sQ[(wv16 + r) * 65 + d] * kv;
    }
    #pragma unroll
    for (int r = 0; r < 16; ++r) {
      float s = sc[r] * 0.125f;
      float m = s;
      for (int off = 32; off; off >>= 1) m = fmaxf(m, __shfl_xor(m, off));
      float e = __expf(s - m);
      float sum = e;
      for (int off = 32; off; off >>= 1) sum += __shfl_xor(sum, off);
      sP[(wv16 + r) * 64 + lane] = f2bf(e / sum);
    }
    __syncthreads();

    // ---- o = P @ V: lane = value dim dv ----
    float oa[16];
    #pragma unroll
    for (int r = 0; r < 16; ++r) oa[r] = 0.f;
    for (int j = 0; j < 64; ++j) {
      float vvv = sV[j * 65 + lane];
      #pragma unroll
      for (int r = 0; r < 16; ++r) oa[r] += bf2f(sP[(wv16 + r) * 64 + j]) * vvv;
    }
    #pragma unroll
    for (int r = 0; r < 16; ++r) sO[(wv16 + r) * 257 + h * 64 + lane] = oa[r];
    __syncthreads();
  }

  // ---- out-proj + residual: lane = token, wave = 64-col block ----
  const int cb = wv * 64;
  float acc[64];
  #pragma unroll
  for (int c = 0; c < 64; ++c) acc[c] = out_b[cb + c];
  for (int co = 0; co < 256; ++co) {
    float ov = sO[lane * 257 + co];
    const float* wr = out_w + co * 256 + cb;               // wave-uniform
    #pragma unroll
    for (int c = 0; c < 64; ++c) acc[c] += ov * wr[c];
  }
  #pragma unroll 4
  for (int c = 0; c < 64; ++c) {
    int ga = (cb + c) * HW + pix;
    img[ga] += acc[c];                                     // x2 = xg + o
  }
}

// ---------------- Kernel C: grouped conv1 (shuffled input) + BN + ReLU ----------------
__global__ __launch_bounds__(256) void kc_conv1(
    const float* __restrict__ x2, const float* __restrict__ w1, const float* __restrict__ b1,
    const float* __restrict__ g1, const float* __restrict__ bb1,
    const float* __restrict__ m1, const float* __restrict__ v1,
    float* __restrict__ y1)
{
  __shared__ float sin_[4 * 70 * 72];
  int wid = blockIdx.x;
  int b = wid >> 6, j = wid & 63;
  const float* img = x2 + (size_t)b * CCH * HW;
  // shuffled-channel inputs for group j: x2 channels {j, 64+j, 128+j, 192+j}
  for (int idx = threadIdx.x; idx < 4 * 70 * 70; idx += 256) {
    int i = idx / 4900, r = idx - i * 4900;
    int yy = r / 70, xx = r - yy * 70;
    int ih = yy - 3, iw = xx - 3;
    float v = 0.f;
    if (ih >= 0 && ih < 64 && iw >= 0 && iw < 64)
      v = img[(i * 64 + j) * HW + ih * 64 + iw];
    sin_[i * 5040 + yy * 72 + xx] = v;
  }
  __syncthreads();

  float inv = g1[j] / sqrtf(v1[j] + 1e-5f);
  float shf = bb1[j] - m1[j] * inv;
  float bia = b1[j];
  float* yo = y1 + ((size_t)b * 64 + j) * HW;
  const float* wbase = w1 + j * 4 * 49;

  for (int it = 0; it < 4; ++it) {
    int s = it * 256 + threadIdx.x;
    int y = s >> 4, x4 = (s & 15) * 4;
    float a0 = 0.f, a1 = 0.f, a2 = 0.f, a3 = 0.f;
    for (int i = 0; i < 4; ++i) {
      #pragma unroll
      for (int ky = 0; ky < 7; ++ky) {
        const float* row = sin_ + i * 5040 + (y + ky) * 72 + x4;
        float v[10];
        #pragma unroll
        for (int q = 0; q < 10; ++q) v[q] = row[q];
        const float* wr = wbase + (i * 7 + ky) * 7;
        #pragma unroll
        for (int kx = 0; kx < 7; ++kx) {
          float wvv = wr[kx];
          a0 += v[kx] * wvv; a1 += v[kx+1] * wvv;
          a2 += v[kx+2] * wvv; a3 += v[kx+3] * wvv;
        }
      }
    }
    int o = y * 64 + x4;
    float4 r4;
    r4.x = fmaxf((a0 + bia) * inv + shf, 0.f);
    r4.y = fmaxf((a1 + bia) * inv + shf, 0.f);
    r4.z = fmaxf((a2 + bia) * inv + shf, 0.f);
    r4.w = fmaxf((a3 + bia) * inv + shf, 0.f);
    *reinterpret_cast<float4*>(yo + o) = r4;
  }
}

// ---------------- Kernel D: grouped conv2 + BN + sigmoid gate * shuffled x2 ----------------
__global__ __launch_bounds__(256) void kd_conv2(
    const float* __restrict__ y1, const float* __restrict__ x2,
    const float* __restrict__ w2, const float* __restrict__ b2,
    const float* __restrict__ g2, const float* __restrict__ bb2,
    const float* __restrict__ m2, const float* __restrict__ v2,
    float* __restrict__ out)
{
  __shared__ float sin_[70 * 72];
  int wid = blockIdx.x;
  int b = wid >> 6, g = wid & 63;
  const float* yin = y1 + ((size_t)b * 64 + g) * HW;
  for (int idx = threadIdx.x; idx < 70 * 70; idx += 256) {
    int yy = idx / 70, xx = idx - yy * 70;
    int ih = yy - 3, iw = xx - 3;
    float v = 0.f;
    if (ih >= 0 && ih < 64 && iw >= 0 && iw < 64) v = yin[ih * 64 + iw];
    sin_[yy * 72 + xx] = v;
  }
  __syncthreads();

  float inv[4], shf[4], bia[4];
  #pragma unroll
  for (int i = 0; i < 4; ++i) {
    int n = 4 * g + i;
    float sc = g2[n] / sqrtf(v2[n] + 1e-5f);
    inv[i] = sc; shf[i] = bb2[n] - m2[n] * sc; bia[i] = b2[n];
  }
  const float* wb = w2 + 4 * g * 49;

  for (int it = 0; it < 4; ++it) {
    int s = it * 256 + threadIdx.x;
    int y = s >> 4, x4 = (s & 15) * 4;
    float acc[4][4] = {};
    #pragma unroll
    for (int ky = 0; ky < 7; ++ky) {
      const float* row = sin_ + (y + ky) * 72 + x4;
      float v[10];
      #pragma unroll
      for (int q = 0; q < 10; ++q) v[q] = row[q];
      #pragma unroll
      for (int i = 0; i < 4; ++i) {
        const float* wr = wb + i * 49 + ky * 7;
        #pragma unroll
        for (int kx = 0; kx < 7; ++kx) {
          float wvv = wr[kx];
          acc[i][0] += v[kx] * wvv; acc[i][1] += v[kx+1] * wvv;
          acc[i][2] += v[kx+2] * wvv; acc[i][3] += v[kx+3] * wvv;
        }
      }
    }
    int po = y * 64 + x4;
    #pragma unroll
    for (int i = 0; i < 4; ++i) {
      int n = 4 * g + i;
      const float* xs = x2 + ((size_t)b * 256 + (i * 64 + g)) * HW + po; // shuffled channel
      float* op = out + ((size_t)b * 256 + n) * HW + po;
      #pragma unroll
      for (int px = 0; px < 4; ++px) {
        float yv = (acc[i][px] + bia[i]) * inv[i] + shf[i];
        op[px] = xs[px] / (1.f + __expf(-yv));
      }
    }
  }
}

extern "C" void kernel_launch(void* const* d_in, const int* in_sizes, int n_in,
                              void* d_out, int out_size, void* d_ws, size_t ws_size,
                              hipStream_t stream) {
  const float* x     = (const float*)d_in[0];
  const float* qkv_w = (const float*)d_in[1];
  const float* qkv_b = (const float*)d_in[2];
  const float* out_w = (const float*)d_in[3];
  const float* out_b = (const float*)d_in[4];
  const float* ca_w1 = (const float*)d_in[5];
  const float* ca_b1 = (const float*)d_in[6];
  const float* ca_w2 = (const float*)d_in[7];
  const float* ca_b2 = (const float*)d_in[8];
  const float* sa_w1 = (const float*)d_in[9];
  const float* sa_b1 = (const float*)d_in[10];
  const float* bn1_g = (const float*)d_in[11];
  const float* bn1_b = (const float*)d_in[12];
  const float* bn1_m = (const float*)d_in[13];
  const float* bn1_v = (const float*)d_in[14];
  const float* sa_w2 = (const float*)d_in[15];
  const float* sa_b2 = (const float*)d_in[16];
  const float* bn2_g = (const float*)d_in[17];
  const float* bn2_b = (const float*)d_in[18];
  const float* bn2_m = (const float*)d_in[19];
  const float* bn2_v = (const float*)d_in[20];

  float* outp = (float*)d_out;
  float* x2 = (float*)d_ws;                              // gated x, then x2 = xg + attn out
  float* y1 = x2 + (size_t)32 * 256 * 4096;              // conv1 output (b,64,64,64)

  ka_ca  <<<512,  256, 0, stream>>>(x, ca_w1, ca_b1, ca_w2, ca_b2, x2);
  kb_attn<<<2048, 256, 0, stream>>>(x2, qkv_w, qkv_b, out_w, out_b);
  kc_conv1<<<2048, 256, 0, stream>>>(x2, sa_w1, sa_b1, bn1_g, bn1_b, bn1_m, bn1_v, y1);
  kd_conv2<<<2048, 256, 0, stream>>>(y1, x2, sa_w2, sa_b2, bn2_g, bn2_b, bn2_m, bn2_v, outp);
}

// Round 2
// 1271.554 us; speedup vs baseline: 6.2180x; 6.2180x over previous
//
#include <hip/hip_runtime.h>

#define HW 4096
#define CCH 256

typedef __bf16 bf16x8 __attribute__((ext_vector_type(8)));
typedef float f32x4 __attribute__((ext_vector_type(4)));
typedef unsigned short u16;

__device__ __forceinline__ u16 f2b(float f) {
  union { float f; unsigned u; } v; v.f = f;
  unsigned r = v.u + 0x7fff + ((v.u >> 16) & 1);   // RNE
  return (u16)(r >> 16);
}

// ---------------- Kernel P: transpose weights to bf16 [out][in] ----------------
__global__ __launch_bounds__(256) void kprep(
    const float* __restrict__ qkv_w, const float* __restrict__ out_w,
    u16* __restrict__ wqkvT, u16* __restrict__ woutT)
{
  int i = blockIdx.x * 256 + threadIdx.x;
  if (i < 768 * 256) {
    int n = i >> 8, c = i & 255;
    wqkvT[i] = f2b(qkv_w[c * 768 + n]);
  }
  if (i < 256 * 256) {
    int n = i >> 8, c = i & 255;
    woutT[i] = f2b(out_w[c * 256 + n]);
  }
}

// ---------------- Kernel A: channel-attention gating: xg = x * sigmoid(MLP(x)) ----------------
__global__ __launch_bounds__(256) void ka_ca(
    const float* __restrict__ x, const float* __restrict__ w1, const float* __restrict__ b1,
    const float* __restrict__ w2, const float* __restrict__ b2, float* __restrict__ xg)
{
  int p = blockIdx.x * 256 + threadIdx.x;
  int b = p >> 12, rem = p & 4095;
  const float* xp = x  + (size_t)b * CCH * HW + rem;
  float*       xo = xg + (size_t)b * CCH * HW + rem;

  float h1[64];
  #pragma unroll
  for (int j = 0; j < 64; ++j) h1[j] = b1[j];

  for (int c = 0; c < 256; ++c) {
    float xv = xp[c * HW];
    const float* wr = w1 + c * 64;
    #pragma unroll
    for (int j = 0; j < 64; ++j) h1[j] += xv * wr[j];
  }
  #pragma unroll
  for (int j = 0; j < 64; ++j) h1[j] = fmaxf(h1[j], 0.f);

  for (int c0 = 0; c0 < 256; c0 += 4) {
    float a0 = b2[c0], a1 = b2[c0+1], a2 = b2[c0+2], a3 = b2[c0+3];
    #pragma unroll 8
    for (int j = 0; j < 64; ++j) {
      float hv = h1[j];
      const float4 w = *reinterpret_cast<const float4*>(w2 + j * 256 + c0);
      a0 += hv * w.x; a1 += hv * w.y; a2 += hv * w.z; a3 += hv * w.w;
    }
    float x0 = xp[(c0+0) * HW], x1v = xp[(c0+1) * HW];
    float x2v = xp[(c0+2) * HW], x3 = xp[(c0+3) * HW];
    xo[(c0+0) * HW] = x0  / (1.f + __expf(-a0));
    xo[(c0+1) * HW] = x1v / (1.f + __expf(-a1));
    xo[(c0+2) * HW] = x2v / (1.f + __expf(-a2));
    xo[(c0+3) * HW] = x3  / (1.f + __expf(-a3));
  }
}

// ---------------- Kernel B: windowed MHSA via MFMA + out-proj + residual (in-place) ----------------
__global__ __launch_bounds__(256, 2) void kb_attn(
    float* __restrict__ x2, const u16* __restrict__ wqkvT, const float* __restrict__ qkv_b,
    const u16* __restrict__ woutT, const float* __restrict__ out_b)
{
  __shared__ u16 sX[64 * 256];   // X window [tok][c], xor-swizzled         32 KB
  __shared__ u16 sQ[64 * 64];    // Q -> P -> O, per-wave strips             8 KB
  __shared__ u16 sK[64 * 64];    //                                          8 KB
  __shared__ u16 sVT[64 * 64];   // V^T [d][tok]                             8 KB

  const int tid = threadIdx.x;
  const int lane = tid & 63;
  const int wv = tid >> 6;
  const int l15 = lane & 15;
  const int lg = lane >> 4;

  const int wid = blockIdx.x;
  const int b = wid >> 6, wrem = wid & 63;
  const int pbase = (wrem >> 3) * (8 * 64) + (wrem & 7) * 8;
  float* img = x2 + (size_t)b * CCH * HW;

  // ---- stage window -> sX ----
  {
    const int tok = lane;
    const int pix = pbase + (tok >> 3) * 64 + (tok & 7);
    const int sw = (tok & 7) << 3;
    for (int p = 0; p < 8; ++p) {
      int c0 = (p * 4 + wv) * 8;
      u16 u[8];
      #pragma unroll
      for (int j = 0; j < 8; ++j) u[j] = f2b(img[(size_t)(c0 + j) * HW + pix]);
      uint4 pk;
      pk.x = u[0] | ((unsigned)u[1] << 16); pk.y = u[2] | ((unsigned)u[3] << 16);
      pk.z = u[4] | ((unsigned)u[5] << 16); pk.w = u[6] | ((unsigned)u[7] << 16);
      *reinterpret_cast<uint4*>(&sX[tok * 256 + (c0 ^ sw)]) = pk;
    }
  }

  // persistent out-proj accumulators (16 tiles x f32x4), init with bias
  f32x4 acc_out[16];
  #pragma unroll
  for (int nt = 0; nt < 16; ++nt) {
    float bias = out_b[nt * 16 + l15];
    f32x4 t; t[0] = bias; t[1] = bias; t[2] = bias; t[3] = bias;
    acc_out[nt] = t;
  }

  __syncthreads();

  const int tokA = wv * 16 + l15;        // strip A-frag row
  const int swA = (tokA & 7) << 3;

  for (int h = 0; h < 4; ++h) {
    // ---------- QKV: wave handles col-tiles wv*3 .. wv*3+2 ----------
    for (int t = 0; t < 4; ++t) {
      bf16x8 a[8];
      int arow = t * 16 + l15;
      int asw = (arow & 7) << 3;
      #pragma unroll
      for (int kb = 0; kb < 8; ++kb) {
        int c0 = kb * 32 + lg * 8;
        a[kb] = *reinterpret_cast<const bf16x8*>(&sX[arow * 256 + (c0 ^ asw)]);
      }
      #pragma unroll
      for (int ti = 0; ti < 3; ++ti) {
        int tau = wv * 3 + ti;
        int kind = tau >> 2, sub = tau & 3;
        int colbase = kind * 256 + h * 64 + sub * 16;
        const u16* wp = wqkvT + (size_t)(colbase + l15) * 256 + lg * 8;
        f32x4 acc = {0.f, 0.f, 0.f, 0.f};
        #pragma unroll
        for (int kb = 0; kb < 8; ++kb) {
          bf16x8 bb = *reinterpret_cast<const bf16x8*>(wp + kb * 32);
          acc = __builtin_amdgcn_mfma_f32_16x16x32_bf16(a[kb], bb, acc, 0, 0, 0);
        }
        float bias = qkv_b[colbase + l15];
        #pragma unroll
        for (int r = 0; r < 4; ++r) {
          int tok = t * 16 + lg * 4 + r;
          u16 uv = f2b(acc[r] + bias);
          int d = sub * 16 + l15;
          if (kind == 0)      sQ [tok * 64 + (d ^ ((tok & 7) << 3))] = uv;
          else if (kind == 1) sK [tok * 64 + (d ^ ((tok & 7) << 3))] = uv;
          else                sVT[d * 64 + (tok ^ ((d & 7) << 3))] = uv;
        }
      }
    }
    __syncthreads();

    // ---------- scores: S = Q @ K^T (strip rows), C col=j, row=tok ----------
    bf16x8 aQ[2];
    #pragma unroll
    for (int kb = 0; kb < 2; ++kb) {
      int d0 = kb * 32 + lg * 8;
      aQ[kb] = *reinterpret_cast<const bf16x8*>(&sQ[tokA * 64 + (d0 ^ swA)]);
    }
    f32x4 s4[4];
    #pragma unroll
    for (int jt = 0; jt < 4; ++jt) {
      int krow = jt * 16 + l15;
      int swk = (krow & 7) << 3;
      f32x4 acc = {0.f, 0.f, 0.f, 0.f};
      #pragma unroll
      for (int kb = 0; kb < 2; ++kb) {
        int d0 = kb * 32 + lg * 8;
        bf16x8 bK = *reinterpret_cast<const bf16x8*>(&sK[krow * 64 + (d0 ^ swk)]);
        acc = __builtin_amdgcn_mfma_f32_16x16x32_bf16(aQ[kb], bK, acc, 0, 0, 0);
      }
      s4[jt] = acc;
    }
    // ---------- softmax per row, P (bf16) overwrites own sQ strip ----------
    #pragma unroll
    for (int r = 0; r < 4; ++r) {
      float m = fmaxf(fmaxf(s4[0][r], s4[1][r]), fmaxf(s4[2][r], s4[3][r]));
      #pragma unroll
      for (int off = 1; off < 16; off <<= 1) m = fmaxf(m, __shfl_xor(m, off));
      float e0 = __expf((s4[0][r] - m) * 0.125f);
      float e1 = __expf((s4[1][r] - m) * 0.125f);
      float e2 = __expf((s4[2][r] - m) * 0.125f);
      float e3 = __expf((s4[3][r] - m) * 0.125f);
      float sum = e0 + e1 + e2 + e3;
      #pragma unroll
      for (int off = 1; off < 16; off <<= 1) sum += __shfl_xor(sum, off);
      float is = 1.f / sum;
      int tok = wv * 16 + lg * 4 + r;
      int swp = (tok & 7) << 3;
      sQ[tok * 64 + ((     l15) ^ swp)] = f2b(e0 * is);
      sQ[tok * 64 + ((16 + l15) ^ swp)] = f2b(e1 * is);
      sQ[tok * 64 + ((32 + l15) ^ swp)] = f2b(e2 * is);
      sQ[tok * 64 + ((48 + l15) ^ swp)] = f2b(e3 * is);
    }
    // ---------- PV: O^T = V^T @ P^T (strip-private, no barrier) ----------
    bf16x8 bP[2];
    #pragma unroll
    for (int kb = 0; kb < 2; ++kb) {
      int j0 = kb * 32 + lg * 8;
      bP[kb] = *reinterpret_cast<const bf16x8*>(&sQ[tokA * 64 + (j0 ^ swA)]);
    }
    f32x4 o4[4];
    #pragma unroll
    for (int dt = 0; dt < 4; ++dt) {
      int drow = dt * 16 + l15;
      int swd = (drow & 7) << 3;
      f32x4 acc = {0.f, 0.f, 0.f, 0.f};
      #pragma unroll
      for (int kb = 0; kb < 2; ++kb) {
        int j0 = kb * 32 + lg * 8;
        bf16x8 aV = *reinterpret_cast<const bf16x8*>(&sVT[drow * 64 + (j0 ^ swd)]);
        acc = __builtin_amdgcn_mfma_f32_16x16x32_bf16(aV, bP[kb], acc, 0, 0, 0);
      }
      o4[dt] = acc;
    }
    // O strip back to sQ as [tok][d] bf16 (packed b64 writes)
    {
      int tok = wv * 16 + l15;
      int swp = (tok & 7) << 3;
      #pragma unroll
      for (int dt = 0; dt < 4; ++dt) {
        int d0 = dt * 16 + lg * 4;
        uint2 pk;
        pk.x = f2b(o4[dt][0]) | ((unsigned)f2b(o4[dt][1]) << 16);
        pk.y = f2b(o4[dt][2]) | ((unsigned)f2b(o4[dt][3]) << 16);
        *reinterpret_cast<uint2*>(&sQ[tok * 64 + (d0 ^ swp)]) = pk;
      }
    }
    // ---------- out-proj partial: acc_out += O_h @ Wout[h*64: , :] ----------
    bf16x8 aO[2];
    #pragma unroll
    for (int kb = 0; kb < 2; ++kb) {
      int d0 = kb * 32 + lg * 8;
      aO[kb] = *reinterpret_cast<const bf16x8*>(&sQ[tokA * 64 + (d0 ^ swA)]);
    }
    #pragma unroll
    for (int nt = 0; nt < 16; ++nt) {
      const u16* wp = woutT + (size_t)(nt * 16 + l15) * 256 + h * 64 + lg * 8;
      #pragma unroll
      for (int kb = 0; kb < 2; ++kb) {
        bf16x8 bW = *reinterpret_cast<const bf16x8*>(wp + kb * 32);
        acc_out[nt] = __builtin_amdgcn_mfma_f32_16x16x32_bf16(aO[kb], bW, acc_out[nt], 0, 0, 0);
      }
    }
    __syncthreads();
  }

  // ---------- epilogue: residual add (f32 global), scatter store ----------
  #pragma unroll
  for (int nt = 0; nt < 16; ++nt) {
    int n = nt * 16 + l15;
    #pragma unroll
    for (int r = 0; r < 4; ++r) {
      int tok = wv * 16 + lg * 4 + r;
      int pix = pbase + (tok >> 3) * 64 + (tok & 7);
      float* p = img + (size_t)n * HW + pix;
      *p += acc_out[nt][r];
    }
  }
}

// ---------------- Kernel C: grouped conv1 (shuffled input) + BN + ReLU ----------------
__global__ __launch_bounds__(256) void kc_conv1(
    const float* __restrict__ x2, const float* __restrict__ w1, const float* __restrict__ b1,
    const float* __restrict__ g1, const float* __restrict__ bb1,
    const float* __restrict__ m1, const float* __restrict__ v1,
    float* __restrict__ y1)
{
  __shared__ float sin_[4 * 70 * 72];
  int wid = blockIdx.x;
  int b = wid >> 6, j = wid & 63;
  const float* img = x2 + (size_t)b * CCH * HW;
  for (int idx = threadIdx.x; idx < 4 * 70 * 70; idx += 256) {
    int i = idx / 4900, r = idx - i * 4900;
    int yy = r / 70, xx = r - yy * 70;
    int ih = yy - 3, iw = xx - 3;
    float v = 0.f;
    if (ih >= 0 && ih < 64 && iw >= 0 && iw < 64)
      v = img[(size_t)(i * 64 + j) * HW + ih * 64 + iw];
    sin_[i * 5040 + yy * 72 + xx] = v;
  }
  __syncthreads();

  float inv = g1[j] / sqrtf(v1[j] + 1e-5f);
  float shf = bb1[j] - m1[j] * inv;
  float bia = b1[j];
  float* yo = y1 + ((size_t)b * 64 + j) * HW;
  const float* wbase = w1 + j * 4 * 49;

  for (int it = 0; it < 4; ++it) {
    int s = it * 256 + threadIdx.x;
    int y = s >> 4, x4 = (s & 15) * 4;
    float a0 = 0.f, a1 = 0.f, a2 = 0.f, a3 = 0.f;
    for (int i = 0; i < 4; ++i) {
      #pragma unroll
      for (int ky = 0; ky < 7; ++ky) {
        const float* row = sin_ + i * 5040 + (y + ky) * 72 + x4;
        float v[10];
        #pragma unroll
        for (int q = 0; q < 10; ++q) v[q] = row[q];
        const float* wr = wbase + (i * 7 + ky) * 7;
        #pragma unroll
        for (int kx = 0; kx < 7; ++kx) {
          float wvv = wr[kx];
          a0 += v[kx] * wvv; a1 += v[kx+1] * wvv;
          a2 += v[kx+2] * wvv; a3 += v[kx+3] * wvv;
        }
      }
    }
    int o = y * 64 + x4;
    float4 r4;
    r4.x = fmaxf((a0 + bia) * inv + shf, 0.f);
    r4.y = fmaxf((a1 + bia) * inv + shf, 0.f);
    r4.z = fmaxf((a2 + bia) * inv + shf, 0.f);
    r4.w = fmaxf((a3 + bia) * inv + shf, 0.f);
    *reinterpret_cast<float4*>(yo + o) = r4;
  }
}

// ---------------- Kernel D: grouped conv2 + BN + sigmoid gate * shuffled x2 ----------------
__global__ __launch_bounds__(256) void kd_conv2(
    const float* __restrict__ y1, const float* __restrict__ x2,
    const float* __restrict__ w2, const float* __restrict__ b2,
    const float* __restrict__ g2, const float* __restrict__ bb2,
    const float* __restrict__ m2, const float* __restrict__ v2,
    float* __restrict__ out)
{
  __shared__ float sin_[70 * 72];
  int wid = blockIdx.x;
  int b = wid >> 6, g = wid & 63;
  const float* yin = y1 + ((size_t)b * 64 + g) * HW;
  for (int idx = threadIdx.x; idx < 70 * 70; idx += 256) {
    int yy = idx / 70, xx = idx - yy * 70;
    int ih = yy - 3, iw = xx - 3;
    float v = 0.f;
    if (ih >= 0 && ih < 64 && iw >= 0 && iw < 64) v = yin[ih * 64 + iw];
    sin_[yy * 72 + xx] = v;
  }
  __syncthreads();

  float inv[4], shf[4], bia[4];
  #pragma unroll
  for (int i = 0; i < 4; ++i) {
    int n = 4 * g + i;
    float sc = g2[n] / sqrtf(v2[n] + 1e-5f);
    inv[i] = sc; shf[i] = bb2[n] - m2[n] * sc; bia[i] = b2[n];
  }
  const float* wb = w2 + 4 * g * 49;

  for (int it = 0; it < 4; ++it) {
    int s = it * 256 + threadIdx.x;
    int y = s >> 4, x4 = (s & 15) * 4;
    float acc[4][4] = {};
    #pragma unroll
    for (int ky = 0; ky < 7; ++ky) {
      const float* row = sin_ + (y + ky) * 72 + x4;
      float v[10];
      #pragma unroll
      for (int q = 0; q < 10; ++q) v[q] = row[q];
      #pragma unroll
      for (int i = 0; i < 4; ++i) {
        const float* wr = wb + i * 49 + ky * 7;
        #pragma unroll
        for (int kx = 0; kx < 7; ++kx) {
          float wvv = wr[kx];
          acc[i][0] += v[kx] * wvv; acc[i][1] += v[kx+1] * wvv;
          acc[i][2] += v[kx+2] * wvv; acc[i][3] += v[kx+3] * wvv;
        }
      }
    }
    int po = y * 64 + x4;
    #pragma unroll
    for (int i = 0; i < 4; ++i) {
      int n = 4 * g + i;
      const float* xs = x2 + ((size_t)b * 256 + (i * 64 + g)) * HW + po;
      float* op = out + ((size_t)b * 256 + n) * HW + po;
      #pragma unroll
      for (int px = 0; px < 4; ++px) {
        float yv = (acc[i][px] + bia[i]) * inv[i] + shf[i];
        op[px] = xs[px] / (1.f + __expf(-yv));
      }
    }
  }
}

extern "C" void kernel_launch(void* const* d_in, const int* in_sizes, int n_in,
                              void* d_out, int out_size, void* d_ws, size_t ws_size,
                              hipStream_t stream) {
  const float* x     = (const float*)d_in[0];
  const float* qkv_w = (const float*)d_in[1];
  const float* qkv_b = (const float*)d_in[2];
  const float* out_w = (const float*)d_in[3];
  const float* out_b = (const float*)d_in[4];
  const float* ca_w1 = (const float*)d_in[5];
  const float* ca_b1 = (const float*)d_in[6];
  const float* ca_w2 = (const float*)d_in[7];
  const float* ca_b2 = (const float*)d_in[8];
  const float* sa_w1 = (const float*)d_in[9];
  const float* sa_b1 = (const float*)d_in[10];
  const float* bn1_g = (const float*)d_in[11];
  const float* bn1_b = (const float*)d_in[12];
  const float* bn1_m = (const float*)d_in[13];
  const float* bn1_v = (const float*)d_in[14];
  const float* sa_w2 = (const float*)d_in[15];
  const float* sa_b2 = (const float*)d_in[16];
  const float* bn2_g = (const float*)d_in[17];
  const float* bn2_b = (const float*)d_in[18];
  const float* bn2_m = (const float*)d_in[19];
  const float* bn2_v = (const float*)d_in[20];

  float* outp = (float*)d_out;
  float* x2 = (float*)d_ws;                         // gated x, then += attn out
  float* y1 = x2 + (size_t)32 * 256 * 4096;         // conv1 output (b,64,64,64)

  // stash transposed bf16 weights in d_out (overwritten by kd at the end)
  u16* wqkvT = (u16*)d_out;                         // 768*256 u16
  u16* woutT = wqkvT + 768 * 256;                   // 256*256 u16

  kprep  <<<768,  256, 0, stream>>>(qkv_w, out_w, wqkvT, woutT);
  ka_ca  <<<512,  256, 0, stream>>>(x, ca_w1, ca_b1, ca_w2, ca_b2, x2);
  kb_attn<<<2048, 256, 0, stream>>>(x2, wqkvT, qkv_b, woutT, out_b);
  kc_conv1<<<2048, 256, 0, stream>>>(x2, sa_w1, sa_b1, bn1_g, bn1_b, bn1_m, bn1_v, y1);
  kd_conv2<<<2048, 256, 0, stream>>>(y1, x2, sa_w2, sa_b2, bn2_g, bn2_b, bn2_m, bn2_v, outp);
}

// Round 3
// 996.388 us; speedup vs baseline: 7.9352x; 1.2762x over previous
//
#include <hip/hip_runtime.h>

#define HW 4096
#define CCH 256

typedef __bf16 bf16x8 __attribute__((ext_vector_type(8)));
typedef float f32x4 __attribute__((ext_vector_type(4)));
typedef unsigned short u16;

__device__ __forceinline__ u16 f2b(float f) {
  union { float f; unsigned u; } v; v.f = f;
  unsigned r = v.u + 0x7fff + ((v.u >> 16) & 1);   // RNE
  return (u16)(r >> 16);
}

// ---------------- Kernel P: bf16 weight relayouts ----------------
// wqkvT[n*256+c] = qkv_w[c][n]; woutT[n*256+c] = out_w[c][n];
// cw1t[n*256+k] = ca_w1[k][n] (n<64); cw2t[n*64+k] = ca_w2[k][n] (n<256)
__global__ __launch_bounds__(256) void kprep(
    const float* __restrict__ qkv_w, const float* __restrict__ out_w,
    const float* __restrict__ ca_w1, const float* __restrict__ ca_w2,
    u16* __restrict__ wqkvT, u16* __restrict__ woutT,
    u16* __restrict__ cw1t, u16* __restrict__ cw2t)
{
  int i = blockIdx.x * 256 + threadIdx.x;
  if (i < 768 * 256) wqkvT[i] = f2b(qkv_w[(i & 255) * 768 + (i >> 8)]);
  if (i < 256 * 256) woutT[i] = f2b(out_w[(i & 255) * 256 + (i >> 8)]);
  if (i < 64 * 256)  cw1t[i]  = f2b(ca_w1[(i & 255) * 64 + (i >> 8)]);
  if (i < 256 * 64)  cw2t[i]  = f2b(ca_w2[(i & 63) * 256 + (i >> 6)]);
}

// ---------------- Kernel B: fused CA-gate + windowed MHSA + out-proj ----------------
// reads raw x, writes x2 = xg + attn_out  (pure store, no residual read)
__global__ __launch_bounds__(256, 2) void kb_fused(
    const float* __restrict__ x, float* __restrict__ x2,
    const u16* __restrict__ wqkvT, const float* __restrict__ qkv_b,
    const u16* __restrict__ woutT, const float* __restrict__ out_b,
    const u16* __restrict__ cw1t, const float* __restrict__ ca_b1,
    const u16* __restrict__ cw2t, const float* __restrict__ ca_b2)
{
  __shared__ u16 sX[64 * 256];   // x -> xg -> O (per-head 64-col slices)   32 KB
  __shared__ u16 sQ[64 * 64];    // H -> Q -> P                              8 KB
  __shared__ u16 sK[64 * 64];    //                                          8 KB
  __shared__ u16 sVT[64 * 64];   // V^T [d][tok]                             8 KB

  const int tid = threadIdx.x;
  const int lane = tid & 63;
  const int wv = __builtin_amdgcn_readfirstlane(tid >> 6);
  const int l15 = lane & 15;
  const int lg = lane >> 4;

  const int wid = blockIdx.x;
  const int b = wid >> 6, wrem = wid & 63;
  const int pbase = (wrem >> 3) * (8 * 64) + (wrem & 7) * 8;
  const float* ximg = x + (size_t)b * CCH * HW;
  float* oimg = x2 + (size_t)b * CCH * HW;

  const int tokA = wv * 16 + l15;          // wave strip row
  const int swA = (tokA & 7) << 3;
  const int pixT = pbase + (tokA >> 3) * 64 + (tokA & 7);

  // ---- stage raw x -> sX (bf16, [tok][c] xor-swizzled) ----
  {
    const int tok = lane;
    const int pix = pbase + (tok >> 3) * 64 + (tok & 7);
    const int sw = (tok & 7) << 3;
    for (int p = 0; p < 8; ++p) {
      int c0 = (p * 4 + wv) * 8;
      u16 u[8];
      #pragma unroll
      for (int j = 0; j < 8; ++j) u[j] = f2b(ximg[(size_t)(c0 + j) * HW + pix]);
      uint4 pk;
      pk.x = u[0] | ((unsigned)u[1] << 16); pk.y = u[2] | ((unsigned)u[3] << 16);
      pk.z = u[4] | ((unsigned)u[5] << 16); pk.w = u[6] | ((unsigned)u[7] << 16);
      *reinterpret_cast<uint4*>(&sX[tok * 256 + (c0 ^ sw)]) = pk;
    }
  }
  __syncthreads();

  // ---- channel-attention gating (per wave, strip-private) ----
  f32x4 acc_out[16];   // (row = out-channel, col = strip token); init xg + out_b
  {
    // layer1: H = relu(X @ W1 + b1), strip rows only
    bf16x8 aXr[8];
    #pragma unroll
    for (int kb = 0; kb < 8; ++kb)
      aXr[kb] = *reinterpret_cast<const bf16x8*>(&sX[tokA * 256 + ((kb * 32 + lg * 8) ^ swA)]);
    #pragma unroll
    for (int nt1 = 0; nt1 < 4; ++nt1) {
      f32x4 c1 = {0.f, 0.f, 0.f, 0.f};
      #pragma unroll
      for (int kb = 0; kb < 8; ++kb) {
        bf16x8 bw = *reinterpret_cast<const bf16x8*>(&cw1t[(nt1 * 16 + l15) * 256 + kb * 32 + lg * 8]);
        c1 = __builtin_amdgcn_mfma_f32_16x16x32_bf16(aXr[kb], bw, c1, 0, 0, 0);
      }
      float bias1 = ca_b1[nt1 * 16 + l15];
      #pragma unroll
      for (int r = 0; r < 4; ++r) {
        int tok = wv * 16 + lg * 4 + r;
        sQ[tok * 64 + ((nt1 * 16 + l15) ^ ((tok & 7) << 3))] = f2b(fmaxf(c1[r] + bias1, 0.f));
      }
    }
    // layer2 (swapped operands -> row = out-channel, col = token) + gate
    bf16x8 hB[2];
    #pragma unroll
    for (int kb = 0; kb < 2; ++kb)
      hB[kb] = *reinterpret_cast<const bf16x8*>(&sQ[tokA * 64 + ((kb * 32 + lg * 8) ^ swA)]);
    #pragma unroll
    for (int nt = 0; nt < 16; ++nt) {
      f32x4 a2 = {0.f, 0.f, 0.f, 0.f};
      #pragma unroll
      for (int kb = 0; kb < 2; ++kb) {
        bf16x8 w2a = *reinterpret_cast<const bf16x8*>(&cw2t[(nt * 16 + l15) * 64 + kb * 32 + lg * 8]);
        a2 = __builtin_amdgcn_mfma_f32_16x16x32_bf16(w2a, hB[kb], a2, 0, 0, 0);
      }
      #pragma unroll
      for (int r = 0; r < 4; ++r) {
        int n = nt * 16 + lg * 4 + r;
        float av = a2[r] + ca_b2[n];
        float xv = ximg[(size_t)n * HW + pixT];           // fp32 x (L1/L2 hot)
        float xg = xv / (1.f + __expf(-av));
        acc_out[nt][r] = xg + out_b[n];
        sX[tokA * 256 + (n ^ swA)] = f2b(xg);             // overwrite own strip row
      }
    }
  }
  __syncthreads();

  // ---- hoist all QKV A-fragments (xg window) into registers ----
  bf16x8 A_all[32];
  #pragma unroll
  for (int t = 0; t < 4; ++t) {
    int arow = t * 16 + l15;
    int asw = (arow & 7) << 3;
    #pragma unroll
    for (int kb = 0; kb < 8; ++kb)
      A_all[t * 8 + kb] = *reinterpret_cast<const bf16x8*>(&sX[arow * 256 + ((kb * 32 + lg * 8) ^ asw)]);
  }
  // sX is now dead as xg storage; O_h slices get written into it per head.

  for (int h = 0; h < 4; ++h) {
    // ---------- QKV: wave owns 3 col-tiles; B loaded once, A from regs ----------
    #pragma unroll
    for (int ti = 0; ti < 3; ++ti) {
      int tau = wv * 3 + ti;
      int kind = tau >> 2, sub = tau & 3;
      int colbase = kind * 256 + h * 64 + sub * 16;
      const u16* wp = wqkvT + (size_t)(colbase + l15) * 256 + lg * 8;
      bf16x8 Bf[8];
      #pragma unroll
      for (int kb = 0; kb < 8; ++kb)
        Bf[kb] = *reinterpret_cast<const bf16x8*>(wp + kb * 32);
      float bias = qkv_b[colbase + l15];
      #pragma unroll
      for (int t = 0; t < 4; ++t) {
        f32x4 acc = {0.f, 0.f, 0.f, 0.f};
        #pragma unroll
        for (int kb = 0; kb < 8; ++kb)
          acc = __builtin_amdgcn_mfma_f32_16x16x32_bf16(A_all[t * 8 + kb], Bf[kb], acc, 0, 0, 0);
        #pragma unroll
        for (int r = 0; r < 4; ++r) {
          int tok = t * 16 + lg * 4 + r;
          u16 uv = f2b(acc[r] + bias);
          int d = sub * 16 + l15;
          int sw = (tok & 7) << 3;
          if (kind == 0)      sQ [tok * 64 + (d ^ sw)] = uv;
          else if (kind == 1) sK [tok * 64 + (d ^ sw)] = uv;
          else                sVT[d * 64 + (tok ^ ((d & 7) << 3))] = uv;
        }
      }
    }
    __syncthreads();

    // ---------- scores S = Q @ K^T (strip rows) ----------
    bf16x8 aQ[2];
    #pragma unroll
    for (int kb = 0; kb < 2; ++kb)
      aQ[kb] = *reinterpret_cast<const bf16x8*>(&sQ[tokA * 64 + ((kb * 32 + lg * 8) ^ swA)]);
    f32x4 s4[4];
    #pragma unroll
    for (int jt = 0; jt < 4; ++jt) {
      int krow = jt * 16 + l15;
      int swk = (krow & 7) << 3;
      f32x4 acc = {0.f, 0.f, 0.f, 0.f};
      #pragma unroll
      for (int kb = 0; kb < 2; ++kb) {
        bf16x8 bK = *reinterpret_cast<const bf16x8*>(&sK[krow * 64 + ((kb * 32 + lg * 8) ^ swk)]);
        acc = __builtin_amdgcn_mfma_f32_16x16x32_bf16(aQ[kb], bK, acc, 0, 0, 0);
      }
      s4[jt] = acc;
    }
    // ---------- softmax per row, P overwrites own sQ strip ----------
    #pragma unroll
    for (int r = 0; r < 4; ++r) {
      float m = fmaxf(fmaxf(s4[0][r], s4[1][r]), fmaxf(s4[2][r], s4[3][r]));
      #pragma unroll
      for (int off = 1; off < 16; off <<= 1) m = fmaxf(m, __shfl_xor(m, off));
      float e0 = __expf((s4[0][r] - m) * 0.125f);
      float e1 = __expf((s4[1][r] - m) * 0.125f);
      float e2 = __expf((s4[2][r] - m) * 0.125f);
      float e3 = __expf((s4[3][r] - m) * 0.125f);
      float sum = e0 + e1 + e2 + e3;
      #pragma unroll
      for (int off = 1; off < 16; off <<= 1) sum += __shfl_xor(sum, off);
      float is = 1.f / sum;
      int tok = wv * 16 + lg * 4 + r;
      int swp = (tok & 7) << 3;
      sQ[tok * 64 + ((     l15) ^ swp)] = f2b(e0 * is);
      sQ[tok * 64 + ((16 + l15) ^ swp)] = f2b(e1 * is);
      sQ[tok * 64 + ((32 + l15) ^ swp)] = f2b(e2 * is);
      sQ[tok * 64 + ((48 + l15) ^ swp)] = f2b(e3 * is);
    }
    // ---------- PV: O^T = V^T @ P^T (strip-private) ----------
    bf16x8 bP[2];
    #pragma unroll
    for (int kb = 0; kb < 2; ++kb)
      bP[kb] = *reinterpret_cast<const bf16x8*>(&sQ[tokA * 64 + ((kb * 32 + lg * 8) ^ swA)]);
    f32x4 o4[4];
    #pragma unroll
    for (int dt = 0; dt < 4; ++dt) {
      int drow = dt * 16 + l15;
      int swd = (drow & 7) << 3;
      f32x4 acc = {0.f, 0.f, 0.f, 0.f};
      #pragma unroll
      for (int kb = 0; kb < 2; ++kb) {
        bf16x8 aV = *reinterpret_cast<const bf16x8*>(&sVT[drow * 64 + ((kb * 32 + lg * 8) ^ swd)]);
        acc = __builtin_amdgcn_mfma_f32_16x16x32_bf16(aV, bP[kb], acc, 0, 0, 0);
      }
      o4[dt] = acc;
    }
    // O_h -> sX[tok][h*64 + d]  (own strip rows)
    #pragma unroll
    for (int dt = 0; dt < 4; ++dt) {
      int d0 = h * 64 + dt * 16 + lg * 4;
      uint2 pk;
      pk.x = f2b(o4[dt][0]) | ((unsigned)f2b(o4[dt][1]) << 16);
      pk.y = f2b(o4[dt][2]) | ((unsigned)f2b(o4[dt][3]) << 16);
      *reinterpret_cast<uint2*>(&sX[tokA * 256 + (d0 ^ swA)]) = pk;
    }
    __syncthreads();
  }

  // ---------- out-proj (K=256, swapped operands) + store x2 = xg + o ----------
  bf16x8 oB[8];
  #pragma unroll
  for (int kb = 0; kb < 8; ++kb)
    oB[kb] = *reinterpret_cast<const bf16x8*>(&sX[tokA * 256 + ((kb * 32 + lg * 8) ^ swA)]);
  #pragma unroll
  for (int nt = 0; nt < 16; ++nt) {
    const u16* wp = woutT + (size_t)(nt * 16 + l15) * 256 + lg * 8;
    f32x4 acc = acc_out[nt];
    #pragma unroll
    for (int kb = 0; kb < 8; ++kb) {
      bf16x8 wA = *reinterpret_cast<const bf16x8*>(wp + kb * 32);
      acc = __builtin_amdgcn_mfma_f32_16x16x32_bf16(wA, oB[kb], acc, 0, 0, 0);
    }
    #pragma unroll
    for (int r = 0; r < 4; ++r) {
      int n = nt * 16 + lg * 4 + r;
      oimg[(size_t)n * HW + pixT] = acc[r];    // pure store, 8x32B segments/instr
    }
  }
}

// ---------------- Kernel C: grouped conv1 + BN + ReLU (quarter tiles) ----------------
__global__ __launch_bounds__(256) void kc_conv1(
    const float* __restrict__ x2, const float* __restrict__ w1, const float* __restrict__ b1,
    const float* __restrict__ g1, const float* __restrict__ bb1,
    const float* __restrict__ m1, const float* __restrict__ v1,
    float* __restrict__ y1)
{
  __shared__ float sin_[4 * 22 * 72];   // 25344 B -> 6 blocks/CU
  int wid = blockIdx.x;
  int b = wid >> 8, rem = wid & 255, j = rem >> 2, qt = rem & 3;
  const float* img = x2 + (size_t)b * CCH * HW;
  // shuffled-channel inputs for group j: x2 channels {j, 64+j, 128+j, 192+j}
  for (int idx = threadIdx.x; idx < 4 * 22 * 70; idx += 256) {
    int i = idx / 1540, r2 = idx - i * 1540;
    int yy = r2 / 70, xx = r2 - yy * 70;
    int ih = qt * 16 + yy - 3, iw = xx - 3;
    float v = 0.f;
    if (ih >= 0 && ih < 64 && iw >= 0 && iw < 64)
      v = img[(size_t)(i * 64 + j) * HW + ih * 64 + iw];
    sin_[(i * 22 + yy) * 72 + xx] = v;
  }
  __syncthreads();

  float inv = g1[j] / sqrtf(v1[j] + 1e-5f);
  float shf = bb1[j] - m1[j] * inv;
  float bia = b1[j];
  float* yo = y1 + ((size_t)b * 64 + j) * HW + qt * 16 * 64;
  const float* wbase = w1 + j * 4 * 49;

  int y = threadIdx.x >> 4, x4 = (threadIdx.x & 15) * 4;
  float a0 = 0.f, a1 = 0.f, a2 = 0.f, a3 = 0.f;
  for (int i = 0; i < 4; ++i) {
    #pragma unroll
    for (int ky = 0; ky < 7; ++ky) {
      const float* row = sin_ + (i * 22 + y + ky) * 72 + x4;
      float v[10];
      #pragma unroll
      for (int q = 0; q < 10; ++q) v[q] = row[q];
      const float* wr = wbase + (i * 7 + ky) * 7;
      #pragma unroll
      for (int kx = 0; kx < 7; ++kx) {
        float wvv = wr[kx];
        a0 += v[kx] * wvv; a1 += v[kx+1] * wvv;
        a2 += v[kx+2] * wvv; a3 += v[kx+3] * wvv;
      }
    }
  }
  float4 r4;
  r4.x = fmaxf((a0 + bia) * inv + shf, 0.f);
  r4.y = fmaxf((a1 + bia) * inv + shf, 0.f);
  r4.z = fmaxf((a2 + bia) * inv + shf, 0.f);
  r4.w = fmaxf((a3 + bia) * inv + shf, 0.f);
  *reinterpret_cast<float4*>(yo + y * 64 + x4) = r4;
}

// ---------------- Kernel D: grouped conv2 + BN + sigmoid gate * shuffled x2 ----------------
__global__ __launch_bounds__(256) void kd_conv2(
    const float* __restrict__ y1, const float* __restrict__ x2,
    const float* __restrict__ w2, const float* __restrict__ b2,
    const float* __restrict__ g2, const float* __restrict__ bb2,
    const float* __restrict__ m2, const float* __restrict__ v2,
    float* __restrict__ out)
{
  __shared__ float sin_[70 * 72];
  int wid = blockIdx.x;
  int b = wid >> 6, g = wid & 63;
  const float* yin = y1 + ((size_t)b * 64 + g) * HW;
  for (int idx = threadIdx.x; idx < 70 * 70; idx += 256) {
    int yy = idx / 70, xx = idx - yy * 70;
    int ih = yy - 3, iw = xx - 3;
    float v = 0.f;
    if (ih >= 0 && ih < 64 && iw >= 0 && iw < 64) v = yin[ih * 64 + iw];
    sin_[yy * 72 + xx] = v;
  }
  __syncthreads();

  float inv[4], shf[4], bia[4];
  #pragma unroll
  for (int i = 0; i < 4; ++i) {
    int n = 4 * g + i;
    float sc = g2[n] / sqrtf(v2[n] + 1e-5f);
    inv[i] = sc; shf[i] = bb2[n] - m2[n] * sc; bia[i] = b2[n];
  }
  const float* wb = w2 + 4 * g * 49;

  for (int it = 0; it < 4; ++it) {
    int s = it * 256 + threadIdx.x;
    int y = s >> 4, x4 = (s & 15) * 4;
    float acc[4][4] = {};
    #pragma unroll
    for (int ky = 0; ky < 7; ++ky) {
      const float* row = sin_ + (y + ky) * 72 + x4;
      float v[10];
      #pragma unroll
      for (int q = 0; q < 10; ++q) v[q] = row[q];
      #pragma unroll
      for (int i = 0; i < 4; ++i) {
        const float* wr = wb + i * 49 + ky * 7;
        #pragma unroll
        for (int kx = 0; kx < 7; ++kx) {
          float wvv = wr[kx];
          acc[i][0] += v[kx] * wvv; acc[i][1] += v[kx+1] * wvv;
          acc[i][2] += v[kx+2] * wvv; acc[i][3] += v[kx+3] * wvv;
        }
      }
    }
    int po = y * 64 + x4;
    #pragma unroll
    for (int i = 0; i < 4; ++i) {
      int n = 4 * g + i;
      const float* xs = x2 + ((size_t)b * 256 + (i * 64 + g)) * HW + po;
      float* op = out + ((size_t)b * 256 + n) * HW + po;
      #pragma unroll
      for (int px = 0; px < 4; ++px) {
        float yv = (acc[i][px] + bia[i]) * inv[i] + shf[i];
        op[px] = xs[px] / (1.f + __expf(-yv));
      }
    }
  }
}

extern "C" void kernel_launch(void* const* d_in, const int* in_sizes, int n_in,
                              void* d_out, int out_size, void* d_ws, size_t ws_size,
                              hipStream_t stream) {
  const float* x     = (const float*)d_in[0];
  const float* qkv_w = (const float*)d_in[1];
  const float* qkv_b = (const float*)d_in[2];
  const float* out_w = (const float*)d_in[3];
  const float* out_b = (const float*)d_in[4];
  const float* ca_w1 = (const float*)d_in[5];
  const float* ca_b1 = (const float*)d_in[6];
  const float* ca_w2 = (const float*)d_in[7];
  const float* ca_b2 = (const float*)d_in[8];
  const float* sa_w1 = (const float*)d_in[9];
  const float* sa_b1 = (const float*)d_in[10];
  const float* bn1_g = (const float*)d_in[11];
  const float* bn1_b = (const float*)d_in[12];
  const float* bn1_m = (const float*)d_in[13];
  const float* bn1_v = (const float*)d_in[14];
  const float* sa_w2 = (const float*)d_in[15];
  const float* sa_b2 = (const float*)d_in[16];
  const float* bn2_g = (const float*)d_in[17];
  const float* bn2_b = (const float*)d_in[18];
  const float* bn2_m = (const float*)d_in[19];
  const float* bn2_v = (const float*)d_in[20];

  float* outp = (float*)d_out;
  float* x2 = (float*)d_ws;                         // xg + attn out
  float* y1 = x2 + (size_t)32 * 256 * 4096;         // conv1 output (b,64,64,64)

  // stash bf16 weight relayouts at the head of d_out (overwritten by kd at the end)
  u16* wqkvT = (u16*)d_out;                         // 196608
  u16* woutT = wqkvT + 768 * 256;                   // 65536
  u16* cw1t  = woutT + 256 * 256;                   // 16384
  u16* cw2t  = cw1t + 64 * 256;                     // 16384

  kprep   <<<768,  256, 0, stream>>>(qkv_w, out_w, ca_w1, ca_w2, wqkvT, woutT, cw1t, cw2t);
  kb_fused<<<2048, 256, 0, stream>>>(x, x2, wqkvT, qkv_b, woutT, out_b, cw1t, ca_b1, cw2t, ca_b2);
  kc_conv1<<<8192, 256, 0, stream>>>(x2, sa_w1, sa_b1, bn1_g, bn1_b, bn1_m, bn1_v, y1);
  kd_conv2<<<2048, 256, 0, stream>>>(y1, x2, sa_w2, sa_b2, bn2_g, bn2_b, bn2_m, bn2_v, outp);
}